// Round 9
// baseline (177.861 us; speedup 1.0000x reference)
//
#include <hip/hip_runtime.h>
#include <stdint.h>

#define BB 8
#define SS 1374
#define DD 384
#define HH 6
#define HDIM 64
#define MROWS (BB*SS)   // 10992
#define NPFX 5
#define SPAD 1376       // padded S for vt rows

typedef __attribute__((ext_vector_type(8))) short bf16x8;
typedef __attribute__((ext_vector_type(4))) float f32x4;
typedef __attribute__((ext_vector_type(4))) unsigned int u32x4;
typedef u32x4 __attribute__((aligned(4))) u32x4_u;

struct MaskT { static constexpr bool value = true; };
struct FullT { static constexpr bool value = false; };

__device__ __forceinline__ unsigned short f2bf(float f){
  union { float f; unsigned int u; } v; v.f = f;
  return (unsigned short)((v.u + 0x7FFFu + ((v.u >> 16) & 1u)) >> 16);
}
__device__ __forceinline__ float bf2f(unsigned short b){
  union { float f; unsigned int u; } v; v.u = ((unsigned int)b) << 16; return v.f;
}
__device__ __forceinline__ unsigned int pk_bf16(float a, float b){
#if __has_builtin(__builtin_amdgcn_cvt_pk_bf16_f32)
  typedef __attribute__((ext_vector_type(2))) __bf16 bfv2;
  bfv2 p = __builtin_amdgcn_cvt_pk_bf16_f32(a, b);
  union { bfv2 v; unsigned int u; } c; c.v = p; return c.u;
#else
  return (unsigned int)f2bf(a) | ((unsigned int)f2bf(b) << 16);
#endif
}

// bijective XCD-chunked remap (m204): consecutive wgid land on the same XCD
__device__ __forceinline__ int xcd_remap(int i, int n){
  int q = n >> 3, r = n & 7;
  int x = i & 7, j = i >> 3;
  return (x < r ? x*(q+1) : r*(q+1) + (x - r)*q) + j;
}

// ---------------- prep: x->bf16 + weighted mean (xbar); 688 blocks for latency hiding ----
__global__ void k_prep(const float* __restrict__ x, unsigned short* __restrict__ xb,
                       float* __restrict__ xbar){
  int b = blockIdx.x / 86, ch = blockIdx.x % 86;
  int d = threadIdx.x;
  int s0 = ch*16, s1 = s0 + 16; if (s1 > SS) s1 = SS;
  float acc = 0.f;
  for (int s = s0; s < s1; ++s){
    float v = x[((size_t)b*SS + s)*DD + d];
    float w = (s == 0) ? (1.f/3.f) : (s < 5) ? (1.f/12.f) : (1.f/4107.f);
    acc += w * v;
    xb[((size_t)b*SS + s)*DD + d] = f2bf(v);
  }
  atomicAdd(&xbar[b*DD + d], acc);
}

// ---------------- coalesced 384x384 transpose (32x32 LDS tiles) for all 4 weight matrices ----
__global__ __launch_bounds__(256) void k_wtrans(const float* __restrict__ wq,
    const float* __restrict__ wk, const float* __restrict__ wv, const float* __restrict__ wo,
    unsigned short* __restrict__ wbT, unsigned short* __restrict__ woT){
  __shared__ float tile[32][33];
  int bid = blockIdx.x;
  int m = bid / 144, tl = bid % 144;
  int tr = tl / 12, tc = tl % 12;
  const float* src = (m==0) ? wq : (m==1) ? wk : (m==2) ? wv : wo;
  unsigned short* dst = (m < 3) ? (wbT + (size_t)m*384*384) : woT;
  int t = threadIdx.x, c = t & 31, r0 = t >> 5;
  #pragma unroll
  for (int p = 0; p < 4; ++p){
    int r = p*8 + r0;
    tile[r][c] = src[(size_t)(tr*32 + r)*384 + tc*32 + c];
  }
  __syncthreads();
  #pragma unroll
  for (int p = 0; p < 4; ++p){
    int r = p*8 + r0;
    dst[(size_t)(tc*32 + r)*384 + tr*32 + c] = f2bf(tile[c][r]);
  }
}

// ---------------- qbar: 48 blocks x 64 threads ----------------
__global__ void k_qbar(const float* __restrict__ xbar, const float* __restrict__ wq,
                       const float* __restrict__ bq, float* __restrict__ qbar){
  __shared__ float xs[DD];
  int b = blockIdx.x / 6, nc = blockIdx.x % 6;
  int t = threadIdx.x;
  for (int i = t; i < DD; i += 64) xs[i] = xbar[b*DD + i];
  __syncthreads();
  int n = nc*64 + t;
  float acc = bq[n];
  for (int d = 0; d < DD; ++d) acc += xs[d]*wq[(size_t)d*384 + n];
  qbar[b*384 + n] = acc;
}

// ---------------- MFMA GEMM ----------------
// MODE 0: fused projections, BN=128 (m93 step: 2x MFMA:ds ratio, half the blocks).
//         nt 0-2=q, 3-5=k, 6-8=v; each 128-col tile = 2 heads. kg epilogue fuses attn-agg.
// MODE 1: output projection, unchanged BN=64 path (R8-proven).
// Both: XCD-chunked remap, lgkm-only K-loop barriers (prefetch vmem spans the barrier).
template<int MODE>
__global__ __launch_bounds__(256) void k_gemm(
    const unsigned short* __restrict__ A, const unsigned short* __restrict__ Bt,
    const float* __restrict__ b0, const float* __restrict__ b1, const float* __restrict__ b2,
    unsigned short* __restrict__ qg, unsigned short* __restrict__ kgp,
    unsigned short* __restrict__ vt, float* __restrict__ out,
    const int* __restrict__ kpat, const float* __restrict__ qbar, float* __restrict__ oagg)
{
  constexpr int NT  = (MODE==0) ? 9 : 6;
  constexpr int BN  = (MODE==0) ? 128 : 64;
  constexpr int NCF = (MODE==0) ? 4 : 2;
  int wg = xcd_remap(blockIdx.x, 86*NT);
  int mt = wg / NT, nt = wg % NT;           // nt-fastest: same A-panel stays on one XCD
  const int t = threadIdx.x;
  const int w = t >> 6, lane = t & 63, quad = lane >> 4, l16 = lane & 15;
  const int wm = w >> 1, wn = w & 1;
  const int m0 = mt*128, n0 = nt*BN;

  // skip V tiles that are entirely in the masked key region (never read by attention)
  if (MODE == 0 && nt >= 6){
    int s0r_ = m0 % SS;
    int SKv = NPFX + kpat[0]; if (SKv > SS) SKv = SS; if (SKv < 1) SKv = 1;
    int lo = (SKv + 63) & ~63;
    if (s0r_ >= lo && s0r_ + 127 < SS) return;   // block-uniform
  }

  constexpr int SMEM_SH = (MODE==0) ? 18432 : 17408;
  __shared__ unsigned short smem[SMEM_SH];
  unsigned short* As = smem;              // [128][72]
  unsigned short* Bs = smem + 9216;       // [BN][72]
  f32x4 acc[4][NCF];
  #pragma unroll
  for (int i=0;i<4;i++)
    #pragma unroll
    for (int j=0;j<NCF;j++) acc[i][j] = (f32x4){0,0,0,0};

  const int ar = t >> 1, akb = (t & 1) * 32;
  int ga = m0 + ar; if (ga > MROWS-1) ga = MROWS-1;
  const unsigned short* ap = A + (size_t)ga*384 + akb;

  u32x4 ra[4];
  #pragma unroll
  for (int i=0;i<4;i++) ra[i] = *(const u32x4*)(ap + i*8);

  if constexpr (MODE == 0){
    const int br = t >> 1, bkb = (t & 1) * 32;
    const unsigned short* bp = Bt + (size_t)(n0 + br)*384 + bkb;
    u32x4 rb[4];
    #pragma unroll
    for (int i=0;i<4;i++) rb[i] = *(const u32x4*)(bp + i*8);

    for (int kc = 0; kc < 6; ++kc){
      asm volatile("s_waitcnt lgkmcnt(0)" ::: "memory");
      __builtin_amdgcn_s_barrier();
      #pragma unroll
      for (int i=0;i<4;i++) *(u32x4*)(As + ar*72 + akb + i*8) = ra[i];
      #pragma unroll
      for (int i=0;i<4;i++) *(u32x4*)(Bs + br*72 + bkb + i*8) = rb[i];
      asm volatile("s_waitcnt lgkmcnt(0)" ::: "memory");
      __builtin_amdgcn_s_barrier();
      if (kc + 1 < 6){
        int kn = (kc+1)*64;
        #pragma unroll
        for (int i=0;i<4;i++) ra[i] = *(const u32x4*)(ap + kn + i*8);
        #pragma unroll
        for (int i=0;i<4;i++) rb[i] = *(const u32x4*)(bp + kn + i*8);
      }
      #pragma unroll
      for (int kh = 0; kh < 2; ++kh){
        bf16x8 af[4], bfr[4];
        #pragma unroll
        for (int rf = 0; rf < 4; ++rf)
          af[rf] = *(const bf16x8*)(As + (wm*64 + rf*16 + l16)*72 + kh*32 + quad*8);
        #pragma unroll
        for (int cf = 0; cf < 4; ++cf)
          bfr[cf] = *(const bf16x8*)(Bs + (wn*64 + cf*16 + l16)*72 + kh*32 + quad*8);
        #pragma unroll
        for (int rf = 0; rf < 4; ++rf)
          #pragma unroll
          for (int cf = 0; cf < 4; ++cf)
            acc[rf][cf] = __builtin_amdgcn_mfma_f32_16x16x32_bf16(af[rf], bfr[cf], acc[rf][cf], 0,0,0);
      }
    }
  } else {
    const int br = t >> 2, bkb = (t & 3) * 16;
    const unsigned short* bp = Bt + (size_t)(n0 + br)*384 + bkb;
    u32x4 rb[2];
    rb[0] = *(const u32x4*)(bp); rb[1] = *(const u32x4*)(bp + 8);

    for (int kc = 0; kc < 6; ++kc){
      asm volatile("s_waitcnt lgkmcnt(0)" ::: "memory");
      __builtin_amdgcn_s_barrier();
      #pragma unroll
      for (int i=0;i<4;i++) *(u32x4*)(As + ar*72 + akb + i*8) = ra[i];
      *(u32x4*)(Bs + br*72 + bkb)     = rb[0];
      *(u32x4*)(Bs + br*72 + bkb + 8) = rb[1];
      asm volatile("s_waitcnt lgkmcnt(0)" ::: "memory");
      __builtin_amdgcn_s_barrier();
      if (kc + 1 < 6){
        int kn = (kc+1)*64;
        #pragma unroll
        for (int i=0;i<4;i++) ra[i] = *(const u32x4*)(ap + kn + i*8);
        rb[0] = *(const u32x4*)(bp + kn); rb[1] = *(const u32x4*)(bp + kn + 8);
      }
      #pragma unroll
      for (int kh = 0; kh < 2; ++kh){
        bf16x8 af[4], bfr[2];
        #pragma unroll
        for (int rf = 0; rf < 4; ++rf)
          af[rf] = *(const bf16x8*)(As + (wm*64 + rf*16 + l16)*72 + kh*32 + quad*8);
        #pragma unroll
        for (int cf = 0; cf < 2; ++cf)
          bfr[cf] = *(const bf16x8*)(Bs + (wn*32 + cf*16 + l16)*72 + kh*32 + quad*8);
        #pragma unroll
        for (int rf = 0; rf < 4; ++rf)
          #pragma unroll
          for (int cf = 0; cf < 2; ++cf)
            acc[rf][cf] = __builtin_amdgcn_mfma_f32_16x16x32_bf16(af[rf], bfr[cf], acc[rf][cf], 0,0,0);
      }
    }
  }

  const int b0r = m0 / SS, s0r = m0 % SS;
  __syncthreads();
  if (MODE == 1){
    float* CsF = (float*)smem;              // [128][68]
    #pragma unroll
    for (int cf = 0; cf < 2; ++cf){
      int e = wn*32 + cf*16 + l16;
      float bias = b0[n0 + e];
      #pragma unroll
      for (int rf = 0; rf < 4; ++rf){
        int rr = wm*64 + rf*16 + quad*4;
        #pragma unroll
        for (int r4 = 0; r4 < 4; ++r4)
          CsF[(rr + r4)*68 + e] = acc[rf][cf][r4] + bias;
      }
    }
    __syncthreads();
    #pragma unroll
    for (int p = 0; p < 8; ++p){
      int r = p*16 + (t >> 4), c = t & 15;
      int rr = m0 + r;
      if (rr < MROWS){
        f32x4 v = *(const f32x4*)(CsF + r*68 + c*4);
        *(f32x4*)(out + (size_t)rr*384 + n0 + c*4) = v;
      }
    }
  } else {
    const int mat = nt / 3, h0 = (nt % 3)*2;
    const float* bvp = (mat==0) ? b0 : (mat==1) ? b1 : b2;
    const float vsc = (mat==0) ? 0.125f : 1.f;
    if (mat < 2){
      unsigned short* Cs = smem;            // [128][136]
      unsigned short* dst = (mat==0) ? qg : kgp;
      #pragma unroll
      for (int cf = 0; cf < 4; ++cf){
        int e = wn*64 + cf*16 + l16;
        float bias = bvp[(h0 + (e>>6))*64 + (e & 63)];
        #pragma unroll
        for (int rf = 0; rf < 4; ++rf){
          int rr = wm*64 + rf*16 + quad*4;
          #pragma unroll
          for (int r4 = 0; r4 < 4; ++r4)
            Cs[(rr + r4)*136 + e] = f2bf((acc[rf][cf][r4] + bias)*vsc);
        }
      }
      __syncthreads();
      #pragma unroll
      for (int p = 0; p < 8; ++p){
        int r = p*16 + (t >> 4), c = t & 15;
        int rr = m0 + r;
        if (rr < MROWS){
          int s = s0r + r, bb = b0r;
          if (s >= SS){ s -= SS; ++bb; }
          int h = h0 + (c >> 3), cc = c & 7;
          u32x4 v = *(const u32x4*)(Cs + r*136 + c*8);
          *(u32x4*)(dst + (((size_t)(bb*HH + h))*SS + s)*64 + cc*8) = v;
          if (mat == 1){
            // fused attn-agg: out_agg[b,s] += (qbar[b,h,:] . kg[b,h,s,:]) / 48
            const float* qh = qbar + bb*384 + h*64 + cc*8;
            float part = 0.f;
            #pragma unroll
            for (int j = 0; j < 4; ++j){
              unsigned int u = v[j];
              part += qh[2*j]     * bf2f((unsigned short)(u & 0xFFFFu));
              part += qh[2*j + 1] * bf2f((unsigned short)(u >> 16));
            }
            part += __shfl_xor(part, 1);
            part += __shfl_xor(part, 2);
            part += __shfl_xor(part, 4);
            if (cc == 0) atomicAdd(oagg + bb*SS + s, part * (1.f/48.f));
          }
        }
      }
    } else {
      unsigned short* CsV = smem;           // [128 e][136 s-pad]
      #pragma unroll
      for (int cf = 0; cf < 4; ++cf){
        int e = wn*64 + cf*16 + l16;
        float bias = bvp[(h0 + (e>>6))*64 + (e & 63)];
        #pragma unroll
        for (int rf = 0; rf < 4; ++rf){
          int rr = wm*64 + rf*16 + quad*4;
          #pragma unroll
          for (int p = 0; p < 2; ++p)
            *(unsigned int*)(CsV + e*136 + rr + p*2) =
                pk_bf16(acc[rf][cf][p*2] + bias, acc[rf][cf][p*2+1] + bias);
        }
      }
      __syncthreads();
      const bool nowrap = (s0r + 127 < SS) && (m0 + 127 < MROWS);
      if (nowrap){
        int e = t >> 1, e64 = e & 63, h = h0 + (e >> 6);
        unsigned short* vrow = vt + ((size_t)(b0r*HH + h)*64 + e64)*SPAD + s0r;
        #pragma unroll
        for (int i = 0; i < 8; ++i){
          int c = (t & 1)*8 + i;
          u32x4 v = *(const u32x4*)(CsV + e*136 + c*8);
          *(u32x4_u*)(vrow + c*8) = v;
        }
      } else {
        for (int idx = t; idx < 128*64; idx += 256){
          int e = idx >> 6, sp = (idx & 63)*2;
          int rr = m0 + sp;
          if (rr < MROWS){
            int s = s0r + sp, bb = b0r;
            if (s >= SS){ s -= SS; ++bb; }
            *(unsigned int*)(vt + ((size_t)(bb*HH + h0 + (e>>6))*64 + (e & 63))*SPAD + s) =
                *(const unsigned int*)(CsV + e*136 + sp);
          }
        }
      }
    }
  }
}

// ---------------- flash attention v12: R4/R5 structure + peeled tail iteration ----------------
#define KSTR 72
__global__ __launch_bounds__(256) void k_attn(
    const unsigned short* __restrict__ qg, const unsigned short* __restrict__ kg,
    const unsigned short* __restrict__ vt, unsigned short* __restrict__ zo,
    const int* __restrict__ kpat)
{
  const int NQB = 22;                   // 4 waves x 16 q rows per block
  int wg = xcd_remap(blockIdx.x, 48*NQB);
  int qb = wg % NQB, bh = wg / NQB;     // same-bh blocks share an XCD -> K/V L2-resident
  int t = threadIdx.x, w = t >> 6, lane = t & 63, quad = lane >> 4, l16 = lane & 15;
  int SK = NPFX + kpat[0]; if (SK > SS) SK = SS; if (SK < 1) SK = 1;
  int niter = (SK + 63) >> 6;
  int nfull = SK >> 6;                  // iterations with no key masking
  __shared__ unsigned short Ks[2][64*KSTR];   // [buf][key][e]
  __shared__ unsigned short Vs[2][64*KSTR];   // [buf][e][key]
  __shared__ unsigned short Ps[4][16*KSTR];   // wave-private P round-trip
  unsigned short* Pw = &Ps[w][0];
  int q0 = qb*64 + w*16;

  bf16x8 aq[2];
  {
    int qrow = q0 + l16; if (qrow > SS-1) qrow = SS-1;
    const unsigned short* p = qg + ((size_t)bh*SS + qrow)*64;
    aq[0] = *(const bf16x8*)(p + quad*8);
    aq[1] = *(const bf16x8*)(p + 32 + quad*8);
  }
  f32x4 o[4];
  float rsum[4] = {0.f,0.f,0.f,0.f};
  #pragma unroll
  for (int i=0;i<4;i++) o[i] = (f32x4){0.f,0.f,0.f,0.f};

  // staging: 256 threads cover 64 rows x 4 quarter-rows of 32B (2 x 16B chunks)
  const int srow = t >> 2, sc = (t & 3) * 16;   // shorts offset within 64-elem row
  const unsigned short* kbase = kg + ((size_t)bh*SS)*64;
  const unsigned short* vbase = vt + ((size_t)bh*64)*SPAD;
  u32x4 rk[2], rv[2];
  {
    rk[0] = *(const u32x4*)(kbase + (size_t)srow*64 + sc);
    rk[1] = *(const u32x4*)(kbase + (size_t)srow*64 + sc + 8);
    rv[0] = *(const u32x4*)(vbase + (size_t)srow*SPAD + sc);
    rv[1] = *(const u32x4*)(vbase + (size_t)srow*SPAD + sc + 8);
  }

  auto step = [&](int it, auto mtag){
    constexpr bool MASKED = decltype(mtag)::value;
    int k0 = it*64;
    int cur = it & 1;
    unsigned short* Ksc = &Ks[cur][0];
    unsigned short* Vsc = &Vs[cur][0];
    *(u32x4*)(Ksc + srow*KSTR + sc)     = rk[0];
    *(u32x4*)(Ksc + srow*KSTR + sc + 8) = rk[1];
    *(u32x4*)(Vsc + srow*KSTR + sc)     = rv[0];
    *(u32x4*)(Vsc + srow*KSTR + sc + 8) = rv[1];
    if (it + 1 < niter){
      int kn = k0 + 64;
      int krow = kn + srow; if (krow > SS-1) krow = SS-1;
      rk[0] = *(const u32x4*)(kbase + (size_t)krow*64 + sc);
      rk[1] = *(const u32x4*)(kbase + (size_t)krow*64 + sc + 8);
      rv[0] = *(const u32x4*)(vbase + (size_t)srow*SPAD + kn + sc);
      rv[1] = *(const u32x4*)(vbase + (size_t)srow*SPAD + kn + sc + 8);
    }
    asm volatile("s_waitcnt lgkmcnt(0)" ::: "memory");
    __builtin_amdgcn_s_barrier();

    #pragma unroll
    for (int ks = 0; ks < 2; ++ks){
      float pp[2][4];
      bf16x8 bkf[2][2];
      #pragma unroll
      for (int ns = 0; ns < 2; ++ns)
        #pragma unroll
        for (int ec = 0; ec < 2; ++ec)
          bkf[ns][ec] = *(const bf16x8*)(Ksc + (ks*32 + 2*l16 + ns)*KSTR + ec*32 + quad*8);
      __builtin_amdgcn_s_setprio(1);
      f32x4 z0 = (f32x4){0.f,0.f,0.f,0.f};
      f32x4 z1 = (f32x4){0.f,0.f,0.f,0.f};
      z0 = __builtin_amdgcn_mfma_f32_16x16x32_bf16(aq[0], bkf[0][0], z0, 0,0,0);
      z0 = __builtin_amdgcn_mfma_f32_16x16x32_bf16(aq[1], bkf[0][1], z0, 0,0,0);
      z1 = __builtin_amdgcn_mfma_f32_16x16x32_bf16(aq[0], bkf[1][0], z1, 0,0,0);
      z1 = __builtin_amdgcn_mfma_f32_16x16x32_bf16(aq[1], bkf[1][1], z1, 0,0,0);
      __builtin_amdgcn_s_setprio(0);
      if constexpr (MASKED){
        bool v0 = (k0 + ks*32 + 2*l16)     < SK;
        bool v1 = (k0 + ks*32 + 2*l16 + 1) < SK;
        #pragma unroll
        for (int rg = 0; rg < 4; ++rg){
          pp[0][rg] = v0 ? __expf(z0[rg]) : 0.f;
          pp[1][rg] = v1 ? __expf(z1[rg]) : 0.f;
        }
      } else {
        #pragma unroll
        for (int rg = 0; rg < 4; ++rg){
          pp[0][rg] = __expf(z0[rg]);
          pp[1][rg] = __expf(z1[rg]);
        }
      }
      #pragma unroll
      for (int rg = 0; rg < 4; ++rg){
        rsum[rg] += pp[0][rg] + pp[1][rg];
        *(unsigned int*)(Pw + (quad*4 + rg)*KSTR + ks*32 + 2*l16) =
            pk_bf16(pp[0][rg], pp[1][rg]);
      }
    }
    #pragma unroll
    for (int kc = 0; kc < 2; ++kc){
      bf16x8 ap = *(const bf16x8*)(Pw + l16*KSTR + kc*32 + quad*8);
      __builtin_amdgcn_s_setprio(1);
      #pragma unroll
      for (int nc = 0; nc < 4; ++nc){
        bf16x8 vf = *(const bf16x8*)(Vsc + (nc*16 + l16)*KSTR + kc*32 + quad*8);
        o[nc] = __builtin_amdgcn_mfma_f32_16x16x32_bf16(ap, vf, o[nc], 0,0,0);
      }
      __builtin_amdgcn_s_setprio(0);
    }
  };

  for (int it = 0; it < nfull; ++it) step(it, FullT{});
  if (nfull < niter) step(nfull, MaskT{});

  // row-sum reduce across 16 col-lanes, then scale+store
  int b = bh / HH, h = bh - (bh/HH)*HH;
  #pragma unroll
  for (int rg = 0; rg < 4; ++rg){
    float s = rsum[rg];
    #pragma unroll
    for (int off = 8; off >= 1; off >>= 1) s += __shfl_xor(s, off);
    int q = q0 + quad*4 + rg;
    if (q >= SS) continue;
    float inv = 1.f / s;
    unsigned short* dst = zo + ((size_t)b*SS + q)*384 + h*64;
    #pragma unroll
    for (int nc = 0; nc < 4; ++nc) dst[nc*16 + l16] = f2bf(o[nc][rg]*inv);
  }
}

// ---------------- launch ----------------
extern "C" void kernel_launch(void* const* d_in, const int* in_sizes, int n_in,
                              void* d_out, int out_size, void* d_ws, size_t ws_size,
                              hipStream_t stream){
  const float* x  = (const float*)d_in[0];
  const float* wq = (const float*)d_in[1];
  const float* bq = (const float*)d_in[2];
  const float* wk = (const float*)d_in[3];
  const float* bk = (const float*)d_in[4];
  const float* wv = (const float*)d_in[5];
  const float* bv = (const float*)d_in[6];
  const float* wo = (const float*)d_in[7];
  const float* bo = (const float*)d_in[8];
  const int* kpat = (const int*)d_in[10];
  float* out = (float*)d_out;
  float* out_agg = out + (size_t)MROWS*DD;

  char* ws = (char*)d_ws;
  unsigned short* xb  = (unsigned short*)(ws);
  unsigned short* wbT = (unsigned short*)(ws +  8441856);
  unsigned short* woT = (unsigned short*)(ws +  9326592);
  unsigned short* qg  = (unsigned short*)(ws +  9621504);
  unsigned short* kg  = (unsigned short*)(ws + 18063360);
  unsigned short* vt  = (unsigned short*)(ws + 26505216);
  unsigned short* zo  = (unsigned short*)(ws + 34959360);
  float* xbar         = (float*)(ws + 43401216);
  float* qbar         = (float*)(ws + 43413504);
  (void)in_sizes; (void)n_in; (void)out_size; (void)ws_size;

  hipMemsetAsync(xbar, 0, BB*DD*sizeof(float), stream);
  hipMemsetAsync(out_agg, 0, BB*SS*sizeof(float), stream);
  k_prep<<<BB*86, 384, 0, stream>>>(x, xb, xbar);
  k_wtrans<<<576, 256, 0, stream>>>(wq, wk, wv, wo, wbT, woT);
  k_qbar<<<48, 64, 0, stream>>>(xbar, wq, bq, qbar);
  k_gemm<0><<<86*9, 256, 0, stream>>>(xb, wbT, bq, bk, bv, qg, kg, vt, nullptr, kpat, qbar, out_agg);
  k_attn<<<48*22, 256, 0, stream>>>(qg, kg, vt, zo, kpat);
  k_gemm<1><<<86*6, 256, 0, stream>>>(zo, woT, bo, nullptr, nullptr, nullptr, nullptr, nullptr, out, nullptr, nullptr, nullptr);
}

// Round 12
// 171.777 us; speedup vs baseline: 1.0354x; 1.0354x over previous
//
#include <hip/hip_runtime.h>
#include <stdint.h>

#define BB 8
#define SS 1374
#define DD 384
#define HH 6
#define HDIM 64
#define MROWS (BB*SS)   // 10992
#define NPFX 5
#define SPAD 1376       // padded S for vt rows

typedef __attribute__((ext_vector_type(8))) short bf16x8;
typedef __attribute__((ext_vector_type(4))) float f32x4;
typedef __attribute__((ext_vector_type(4))) unsigned int u32x4;
typedef u32x4 __attribute__((aligned(4))) u32x4_u;

struct MaskT { static constexpr bool value = true; };
struct FullT { static constexpr bool value = false; };

__device__ __forceinline__ unsigned short f2bf(float f){
  union { float f; unsigned int u; } v; v.f = f;
  return (unsigned short)((v.u + 0x7FFFu + ((v.u >> 16) & 1u)) >> 16);
}
__device__ __forceinline__ float bf2f(unsigned short b){
  union { float f; unsigned int u; } v; v.u = ((unsigned int)b) << 16; return v.f;
}
__device__ __forceinline__ unsigned int pk_bf16(float a, float b){
#if __has_builtin(__builtin_amdgcn_cvt_pk_bf16_f32)
  typedef __attribute__((ext_vector_type(2))) __bf16 bfv2;
  bfv2 p = __builtin_amdgcn_cvt_pk_bf16_f32(a, b);
  union { bfv2 v; unsigned int u; } c; c.v = p; return c.u;
#else
  return (unsigned int)f2bf(a) | ((unsigned int)f2bf(b) << 16);
#endif
}

// bijective XCD-chunked remap (m204): consecutive wgid land on the same XCD
__device__ __forceinline__ int xcd_remap(int i, int n){
  int q = n >> 3, r = n & 7;
  int x = i & 7, j = i >> 3;
  return (x < r ? x*(q+1) : r*(q+1) + (x - r)*q) + j;
}

// ---------------- prep: x->bf16 + weighted mean (xbar); 688 blocks for latency hiding ----
__global__ void k_prep(const float* __restrict__ x, unsigned short* __restrict__ xb,
                       float* __restrict__ xbar){
  int b = blockIdx.x / 86, ch = blockIdx.x % 86;
  int d = threadIdx.x;
  int s0 = ch*16, s1 = s0 + 16; if (s1 > SS) s1 = SS;
  float acc = 0.f;
  for (int s = s0; s < s1; ++s){
    float v = x[((size_t)b*SS + s)*DD + d];
    float w = (s == 0) ? (1.f/3.f) : (s < 5) ? (1.f/12.f) : (1.f/4107.f);
    acc += w * v;
    xb[((size_t)b*SS + s)*DD + d] = f2bf(v);
  }
  atomicAdd(&xbar[b*DD + d], acc);
}

// ---------------- coalesced 384x384 transpose (32x32 LDS tiles) for all 4 weight matrices ----
__global__ __launch_bounds__(256) void k_wtrans(const float* __restrict__ wq,
    const float* __restrict__ wk, const float* __restrict__ wv, const float* __restrict__ wo,
    unsigned short* __restrict__ wbT, unsigned short* __restrict__ woT){
  __shared__ float tile[32][33];
  int bid = blockIdx.x;
  int m = bid / 144, tl = bid % 144;
  int tr = tl / 12, tc = tl % 12;
  const float* src = (m==0) ? wq : (m==1) ? wk : (m==2) ? wv : wo;
  unsigned short* dst = (m < 3) ? (wbT + (size_t)m*384*384) : woT;
  int t = threadIdx.x, c = t & 31, r0 = t >> 5;
  #pragma unroll
  for (int p = 0; p < 4; ++p){
    int r = p*8 + r0;
    tile[r][c] = src[(size_t)(tr*32 + r)*384 + tc*32 + c];
  }
  __syncthreads();
  #pragma unroll
  for (int p = 0; p < 4; ++p){
    int r = p*8 + r0;
    dst[(size_t)(tc*32 + r)*384 + tr*32 + c] = f2bf(tile[c][r]);
  }
}

// ---------------- qbar: 48 blocks x 64 threads (was 8 blocks -> grid-starved) ----------------
__global__ void k_qbar(const float* __restrict__ xbar, const float* __restrict__ wq,
                       const float* __restrict__ bq, float* __restrict__ qbar){
  __shared__ float xs[DD];
  int b = blockIdx.x / 6, nc = blockIdx.x % 6;
  int t = threadIdx.x;
  for (int i = t; i < DD; i += 64) xs[i] = xbar[b*DD + i];
  __syncthreads();
  int n = nc*64 + t;
  float acc = bq[n];
  for (int d = 0; d < DD; ++d) acc += xs[d]*wq[(size_t)d*384 + n];
  qbar[b*384 + n] = acc;
}

// ---------------- MFMA GEMM: 128x64 tile, BK=64 (6 iters), reg prefetch, coalesced epilogue ----
// MODE 0: fused projections (q/k/v); kg epilogue also accumulates the attn-agg dot.
// MODE 1: output projection. Both use XCD-chunked block remap and lgkm-only K-loop barriers
// (prefetch vmem spans the barrier; reg-dep at ds_write enforces completion).
template<int MODE>
__global__ __launch_bounds__(256) void k_gemm(
    const unsigned short* __restrict__ A, const unsigned short* __restrict__ Bt,
    const float* __restrict__ b0, const float* __restrict__ b1, const float* __restrict__ b2,
    unsigned short* __restrict__ qg, unsigned short* __restrict__ kgp,
    unsigned short* __restrict__ vt, float* __restrict__ out,
    const int* __restrict__ kpat, const float* __restrict__ qbar, float* __restrict__ oagg)
{
  const int NT = (MODE==0) ? 18 : 6;
  int wg = xcd_remap(blockIdx.x, 86*NT);
  int mt = wg / NT, nt = wg % NT;           // nt-fastest: same A-panel stays on one XCD
  const int t = threadIdx.x;
  const int w = t >> 6, lane = t & 63, quad = lane >> 4, l16 = lane & 15;
  const int wm = w >> 1, wn = w & 1;
  const int m0 = mt*128, n0 = nt*64;

  // skip V tiles that are entirely in the masked key region (never read by attention)
  if (MODE == 0 && nt >= 12){
    int s0r_ = m0 % SS;
    int SKv = NPFX + kpat[0]; if (SKv > SS) SKv = SS; if (SKv < 1) SKv = 1;
    int lo = (SKv + 63) & ~63;
    if (s0r_ >= lo && s0r_ + 127 < SS) return;   // block-uniform
  }

  constexpr int SMEM_SH = (MODE==0) ? 13824 : 17408;
  __shared__ unsigned short smem[SMEM_SH];
  unsigned short* As = smem;              // [128][72]
  unsigned short* Bs = smem + 9216;       // [64][72]
  f32x4 acc[4][2];
  #pragma unroll
  for (int i=0;i<4;i++){ acc[i][0] = (f32x4){0,0,0,0}; acc[i][1] = (f32x4){0,0,0,0}; }

  const int ar = t >> 1, akb = (t & 1) * 32;
  int ga = m0 + ar; if (ga > MROWS-1) ga = MROWS-1;
  const unsigned short* ap = A + (size_t)ga*384 + akb;
  const int br = t >> 2, bkb = (t & 3) * 16;
  const unsigned short* bp = Bt + (size_t)(n0 + br)*384 + bkb;

  u32x4 ra[4], rb[2];
  #pragma unroll
  for (int i=0;i<4;i++) ra[i] = *(const u32x4*)(ap + i*8);
  rb[0] = *(const u32x4*)(bp); rb[1] = *(const u32x4*)(bp + 8);

  for (int kc = 0; kc < 6; ++kc){
    // prev iter's LDS reads are retired (lgkm waits precede their MFMAs); raw barrier only
    asm volatile("s_waitcnt lgkmcnt(0)" ::: "memory");
    __builtin_amdgcn_s_barrier();
    #pragma unroll
    for (int i=0;i<4;i++) *(u32x4*)(As + ar*72 + akb + i*8) = ra[i];
    *(u32x4*)(Bs + br*72 + bkb)     = rb[0];
    *(u32x4*)(Bs + br*72 + bkb + 8) = rb[1];
    asm volatile("s_waitcnt lgkmcnt(0)" ::: "memory");
    __builtin_amdgcn_s_barrier();
    if (kc + 1 < 6){
      int kn = (kc+1)*64;
      #pragma unroll
      for (int i=0;i<4;i++) ra[i] = *(const u32x4*)(ap + kn + i*8);
      rb[0] = *(const u32x4*)(bp + kn); rb[1] = *(const u32x4*)(bp + kn + 8);
    }
    #pragma unroll
    for (int kh = 0; kh < 2; ++kh){
      bf16x8 af[4], bfr[2];
      #pragma unroll
      for (int rf = 0; rf < 4; ++rf)
        af[rf] = *(const bf16x8*)(As + (wm*64 + rf*16 + l16)*72 + kh*32 + quad*8);
      #pragma unroll
      for (int cf = 0; cf < 2; ++cf)
        bfr[cf] = *(const bf16x8*)(Bs + (wn*32 + cf*16 + l16)*72 + kh*32 + quad*8);
      #pragma unroll
      for (int rf = 0; rf < 4; ++rf)
        #pragma unroll
        for (int cf = 0; cf < 2; ++cf)
          acc[rf][cf] = __builtin_amdgcn_mfma_f32_16x16x32_bf16(af[rf], bfr[cf], acc[rf][cf], 0,0,0);
    }
  }

  const int b0r = m0 / SS, s0r = m0 % SS;
  __syncthreads();
  if (MODE == 1){
    float* CsF = (float*)smem;              // [128][68]
    #pragma unroll
    for (int cf = 0; cf < 2; ++cf){
      int e = wn*32 + cf*16 + l16;
      float bias = b0[n0 + e];
      #pragma unroll
      for (int rf = 0; rf < 4; ++rf){
        int rr = wm*64 + rf*16 + quad*4;
        #pragma unroll
        for (int r4 = 0; r4 < 4; ++r4)
          CsF[(rr + r4)*68 + e] = acc[rf][cf][r4] + bias;
      }
    }
    __syncthreads();
    #pragma unroll
    for (int p = 0; p < 8; ++p){
      int r = p*16 + (t >> 4), c = t & 15;
      int rr = m0 + r;
      if (rr < MROWS){
        f32x4 v = *(const f32x4*)(CsF + r*68 + c*4);
        *(f32x4*)(out + (size_t)rr*384 + n0 + c*4) = v;
      }
    }
  } else {
    const int mat = nt / 6, h = nt - mat*6;
    const float* bvp = (mat==0) ? b0 : (mat==1) ? b1 : b2;
    const float vsc = (mat==0) ? 0.125f : 1.f;
    if (mat < 2){
      unsigned short* Cs = As;
      unsigned short* dst = (mat==0) ? qg : kgp;
      #pragma unroll
      for (int cf = 0; cf < 2; ++cf){
        int e = wn*32 + cf*16 + l16;
        float bias = bvp[h*64 + e];
        #pragma unroll
        for (int rf = 0; rf < 4; ++rf){
          int rr = wm*64 + rf*16 + quad*4;
          #pragma unroll
          for (int r4 = 0; r4 < 4; ++r4)
            Cs[(rr + r4)*72 + e] = f2bf((acc[rf][cf][r4] + bias)*vsc);
        }
      }
      __syncthreads();
      #pragma unroll
      for (int p = 0; p < 4; ++p){
        int r = p*32 + (t >> 3), c = t & 7;
        int rr = m0 + r;
        if (rr < MROWS){
          int s = s0r + r, bb = b0r;
          if (s >= SS){ s -= SS; ++bb; }
          u32x4 v = *(const u32x4*)(Cs + r*72 + c*8);
          *(u32x4*)(dst + (((size_t)(bb*HH + h))*SS + s)*64 + c*8) = v;
          if (mat == 1){
            // fused attn-agg: out_agg[b,s] += (qbar[b,h,:] . kg[b,h,s,:]) / 48
            const float* qh = qbar + bb*384 + h*64 + c*8;
            float part = 0.f;
            #pragma unroll
            for (int j = 0; j < 4; ++j){
              unsigned int u = v[j];
              part += qh[2*j]     * bf2f((unsigned short)(u & 0xFFFFu));
              part += qh[2*j + 1] * bf2f((unsigned short)(u >> 16));
            }
            part += __shfl_xor(part, 1);
            part += __shfl_xor(part, 2);
            part += __shfl_xor(part, 4);
            if (c == 0) atomicAdd(oagg + bb*SS + s, part * (1.f/48.f));
          }
        }
      }
    } else {
      unsigned short* CsV = As;               // [64 e][136 s-pad]
      #pragma unroll
      for (int cf = 0; cf < 2; ++cf){
        int e = wn*32 + cf*16 + l16;
        float bias = bvp[h*64 + e];
        #pragma unroll
        for (int rf = 0; rf < 4; ++rf){
          int rr = wm*64 + rf*16 + quad*4;
          #pragma unroll
          for (int p = 0; p < 2; ++p)
            *(unsigned int*)(CsV + e*136 + rr + p*2) =
                pk_bf16(acc[rf][cf][p*2] + bias, acc[rf][cf][p*2+1] + bias);
        }
      }
      __syncthreads();
      const bool nowrap = (s0r + 127 < SS) && (m0 + 127 < MROWS);
      if (nowrap){
        int e = t >> 2;
        unsigned short* vrow = vt + ((size_t)(b0r*HH + h)*64 + e)*SPAD + s0r;
        #pragma unroll
        for (int i = 0; i < 4; ++i){
          int c = (t & 3)*4 + i;
          u32x4 v = *(const u32x4*)(CsV + e*136 + c*8);
          *(u32x4_u*)(vrow + c*8) = v;
        }
      } else {
        for (int idx = t; idx < 64*64; idx += 256){
          int e = idx >> 6, sp = (idx & 63)*2;
          int rr = m0 + sp;
          if (rr < MROWS){
            int s = s0r + sp, bb = b0r;
            if (s >= SS){ s -= SS; ++bb; }
            *(unsigned int*)(vt + ((size_t)(bb*HH + h)*64 + e)*SPAD + s) =
                *(const unsigned int*)(CsV + e*136 + sp);
          }
        }
      }
    }
  }
}

// ---------------- flash attention v12: R4/R5 structure + peeled tail iteration ----------------
// (1056 blocks, 4 waves x 16 q, dbuf K/V, 1 lgkm-only barrier/iter, setprio around MFMA.)
// Full iterations (k0+64 <= SK) drop the per-key valid compares/cndmasks at compile time;
// only the final partial chunk keeps masking.
#define KSTR 72
__global__ __launch_bounds__(256) void k_attn(
    const unsigned short* __restrict__ qg, const unsigned short* __restrict__ kg,
    const unsigned short* __restrict__ vt, unsigned short* __restrict__ zo,
    const int* __restrict__ kpat)
{
  const int NQB = 22;                   // 4 waves x 16 q rows per block
  int wg = xcd_remap(blockIdx.x, 48*NQB);
  int qb = wg % NQB, bh = wg / NQB;     // same-bh blocks share an XCD -> K/V L2-resident
  int t = threadIdx.x, w = t >> 6, lane = t & 63, quad = lane >> 4, l16 = lane & 15;
  int SK = NPFX + kpat[0]; if (SK > SS) SK = SS; if (SK < 1) SK = 1;
  int niter = (SK + 63) >> 6;
  int nfull = SK >> 6;                  // iterations with no key masking
  __shared__ unsigned short Ks[2][64*KSTR];   // [buf][key][e]
  __shared__ unsigned short Vs[2][64*KSTR];   // [buf][e][key]
  __shared__ unsigned short Ps[4][16*KSTR];   // wave-private P round-trip
  unsigned short* Pw = &Ps[w][0];
  int q0 = qb*64 + w*16;

  bf16x8 aq[2];
  {
    int qrow = q0 + l16; if (qrow > SS-1) qrow = SS-1;
    const unsigned short* p = qg + ((size_t)bh*SS + qrow)*64;
    aq[0] = *(const bf16x8*)(p + quad*8);
    aq[1] = *(const bf16x8*)(p + 32 + quad*8);
  }
  f32x4 o[4];
  float rsum[4] = {0.f,0.f,0.f,0.f};
  #pragma unroll
  for (int i=0;i<4;i++) o[i] = (f32x4){0.f,0.f,0.f,0.f};

  // staging: 256 threads cover 64 rows x 4 quarter-rows of 32B (2 x 16B chunks)
  const int srow = t >> 2, sc = (t & 3) * 16;   // shorts offset within 64-elem row
  const unsigned short* kbase = kg + ((size_t)bh*SS)*64;
  const unsigned short* vbase = vt + ((size_t)bh*64)*SPAD;
  u32x4 rk[2], rv[2];
  {
    rk[0] = *(const u32x4*)(kbase + (size_t)srow*64 + sc);
    rk[1] = *(const u32x4*)(kbase + (size_t)srow*64 + sc + 8);
    rv[0] = *(const u32x4*)(vbase + (size_t)srow*SPAD + sc);
    rv[1] = *(const u32x4*)(vbase + (size_t)srow*SPAD + sc + 8);
  }

  auto step = [&](int it, auto mtag){
    constexpr bool MASKED = decltype(mtag)::value;
    int k0 = it*64;
    int cur = it & 1;
    unsigned short* Ksc = &Ks[cur][0];
    unsigned short* Vsc = &Vs[cur][0];
    // write this iter's chunk (loaded to regs last iter / prologue)
    *(u32x4*)(Ksc + srow*KSTR + sc)     = rk[0];
    *(u32x4*)(Ksc + srow*KSTR + sc + 8) = rk[1];
    *(u32x4*)(Vsc + srow*KSTR + sc)     = rv[0];
    *(u32x4*)(Vsc + srow*KSTR + sc + 8) = rv[1];
    // prefetch next chunk BEFORE the barrier: lgkm-only drain leaves these vmem loads
    // in flight across the barrier; they are waited on (reg dep) at next iter's ds_write.
    if (it + 1 < niter){
      int kn = k0 + 64;
      int krow = kn + srow; if (krow > SS-1) krow = SS-1;
      rk[0] = *(const u32x4*)(kbase + (size_t)krow*64 + sc);
      rk[1] = *(const u32x4*)(kbase + (size_t)krow*64 + sc + 8);
      rv[0] = *(const u32x4*)(vbase + (size_t)srow*SPAD + kn + sc);
      rv[1] = *(const u32x4*)(vbase + (size_t)srow*SPAD + kn + sc + 8);
    }
    // writer-side LDS drain + raw barrier (no vmcnt(0) drain, unlike __syncthreads)
    asm volatile("s_waitcnt lgkmcnt(0)" ::: "memory");
    __builtin_amdgcn_s_barrier();

    // QK^T: subtile ks covers keys k0 + ks*32 + 2*l16 + ns
    #pragma unroll
    for (int ks = 0; ks < 2; ++ks){
      float pp[2][4];
      bf16x8 bkf[2][2];
      #pragma unroll
      for (int ns = 0; ns < 2; ++ns)
        #pragma unroll
        for (int ec = 0; ec < 2; ++ec)
          bkf[ns][ec] = *(const bf16x8*)(Ksc + (ks*32 + 2*l16 + ns)*KSTR + ec*32 + quad*8);
      __builtin_amdgcn_s_setprio(1);
      f32x4 z0 = (f32x4){0.f,0.f,0.f,0.f};
      f32x4 z1 = (f32x4){0.f,0.f,0.f,0.f};
      z0 = __builtin_amdgcn_mfma_f32_16x16x32_bf16(aq[0], bkf[0][0], z0, 0,0,0);
      z0 = __builtin_amdgcn_mfma_f32_16x16x32_bf16(aq[1], bkf[0][1], z0, 0,0,0);
      z1 = __builtin_amdgcn_mfma_f32_16x16x32_bf16(aq[0], bkf[1][0], z1, 0,0,0);
      z1 = __builtin_amdgcn_mfma_f32_16x16x32_bf16(aq[1], bkf[1][1], z1, 0,0,0);
      __builtin_amdgcn_s_setprio(0);
      if constexpr (MASKED){
        bool v0 = (k0 + ks*32 + 2*l16)     < SK;
        bool v1 = (k0 + ks*32 + 2*l16 + 1) < SK;
        #pragma unroll
        for (int rg = 0; rg < 4; ++rg){
          pp[0][rg] = v0 ? __expf(z0[rg]) : 0.f;
          pp[1][rg] = v1 ? __expf(z1[rg]) : 0.f;
        }
      } else {
        #pragma unroll
        for (int rg = 0; rg < 4; ++rg){
          pp[0][rg] = __expf(z0[rg]);
          pp[1][rg] = __expf(z1[rg]);
        }
      }
      #pragma unroll
      for (int rg = 0; rg < 4; ++rg){
        rsum[rg] += pp[0][rg] + pp[1][rg];
        *(unsigned int*)(Pw + (quad*4 + rg)*KSTR + ks*32 + 2*l16) =
            pk_bf16(pp[0][rg], pp[1][rg]);
      }
    }
    // PV (P via wave-private LDS round-trip; no extra barrier)
    #pragma unroll
    for (int kc = 0; kc < 2; ++kc){
      bf16x8 ap = *(const bf16x8*)(Pw + l16*KSTR + kc*32 + quad*8);
      __builtin_amdgcn_s_setprio(1);
      #pragma unroll
      for (int nc = 0; nc < 4; ++nc){
        bf16x8 vf = *(const bf16x8*)(Vsc + (nc*16 + l16)*KSTR + kc*32 + quad*8);
        o[nc] = __builtin_amdgcn_mfma_f32_16x16x32_bf16(ap, vf, o[nc], 0,0,0);
      }
      __builtin_amdgcn_s_setprio(0);
    }
  };

  for (int it = 0; it < nfull; ++it) step(it, FullT{});
  if (nfull < niter) step(nfull, MaskT{});

  // row-sum reduce across 16 col-lanes, then scale+store
  int b = bh / HH, h = bh - (bh/HH)*HH;
  #pragma unroll
  for (int rg = 0; rg < 4; ++rg){
    float s = rsum[rg];
    #pragma unroll
    for (int off = 8; off >= 1; off >>= 1) s += __shfl_xor(s, off);
    int q = q0 + quad*4 + rg;
    if (q >= SS) continue;
    float inv = 1.f / s;
    unsigned short* dst = zo + ((size_t)b*SS + q)*384 + h*64;
    #pragma unroll
    for (int nc = 0; nc < 4; ++nc) dst[nc*16 + l16] = f2bf(o[nc][rg]*inv);
  }
}

// ---------------- launch ----------------
extern "C" void kernel_launch(void* const* d_in, const int* in_sizes, int n_in,
                              void* d_out, int out_size, void* d_ws, size_t ws_size,
                              hipStream_t stream){
  const float* x  = (const float*)d_in[0];
  const float* wq = (const float*)d_in[1];
  const float* bq = (const float*)d_in[2];
  const float* wk = (const float*)d_in[3];
  const float* bk = (const float*)d_in[4];
  const float* wv = (const float*)d_in[5];
  const float* bv = (const float*)d_in[6];
  const float* wo = (const float*)d_in[7];
  const float* bo = (const float*)d_in[8];
  const int* kpat = (const int*)d_in[10];
  float* out = (float*)d_out;
  float* out_agg = out + (size_t)MROWS*DD;

  char* ws = (char*)d_ws;
  unsigned short* xb  = (unsigned short*)(ws);
  unsigned short* wbT = (unsigned short*)(ws +  8441856);
  unsigned short* woT = (unsigned short*)(ws +  9326592);
  unsigned short* qg  = (unsigned short*)(ws +  9621504);
  unsigned short* kg  = (unsigned short*)(ws + 18063360);
  unsigned short* vt  = (unsigned short*)(ws + 26505216);
  unsigned short* zo  = (unsigned short*)(ws + 34959360);
  float* xbar         = (float*)(ws + 43401216);
  float* qbar         = (float*)(ws + 43413504);
  (void)in_sizes; (void)n_in; (void)out_size; (void)ws_size;

  hipMemsetAsync(xbar, 0, BB*DD*sizeof(float), stream);
  hipMemsetAsync(out_agg, 0, BB*SS*sizeof(float), stream);
  k_prep<<<BB*86, 384, 0, stream>>>(x, xb, xbar);
  k_wtrans<<<576, 256, 0, stream>>>(wq, wk, wv, wo, wbT, woT);
  k_qbar<<<48, 64, 0, stream>>>(xbar, wq, bq, qbar);
  k_gemm<0><<<86*18, 256, 0, stream>>>(xb, wbT, bq, bk, bv, qg, kg, vt, nullptr, kpat, qbar, out_agg);
  k_attn<<<48*22, 256, 0, stream>>>(qg, kg, vt, zo, kpat);
  k_gemm<1><<<86*6, 256, 0, stream>>>(zo, woT, bo, nullptr, nullptr, nullptr, nullptr, nullptr, out, nullptr, nullptr, nullptr);
}